// Round 6
// baseline (629.248 us; speedup 1.0000x reference)
//
#include <hip/hip_runtime.h>

#define CDIM 64
#define SLOPE 0.2f

__device__ __forceinline__ float lrelu(float v) { return v > 0.f ? v : SLOPE * v; }

// ---------------------------------------------------------------------------
// Tiled dual GEMM, shuffle-free: Ya = X@Wa, Yb = X@Wb.
// ---------------------------------------------------------------------------
__global__ void gemm64x2_tiled(const float* __restrict__ X,
                               const float* __restrict__ Wa, float* __restrict__ Ya,
                               const float* __restrict__ Wb, float* __restrict__ Yb,
                               int n)
{
    __shared__ float sX[64 * 68];
    __shared__ float sWaT[64 * 66];
    __shared__ float sWbT[64 * 66];
    const int tid = threadIdx.x;
    const int lane = tid & 63;
    const int q = tid >> 6;

    for (int idx = tid; idx < 4096; idx += 256) {
        int k = idx >> 6, c = idx & 63;
        sWaT[c * 66 + k] = Wa[idx];
        sWbT[c * 66 + k] = Wb[idx];
    }

    const int ntiles = (n + 63) >> 6;
    for (int tile = blockIdx.x; tile < ntiles; tile += gridDim.x) {
        const int rowbase = tile << 6;
        __syncthreads();
#pragma unroll
        for (int i = 0; i < 4; ++i) {
            int f = tid + i * 256;
            int r = f >> 4, k4 = f & 15;
            int row = rowbase + r;
            float4 v = make_float4(0.f, 0.f, 0.f, 0.f);
            if (row < n) v = *reinterpret_cast<const float4*>(X + (size_t)row * 64 + k4 * 4);
            *reinterpret_cast<float4*>(&sX[r * 68 + k4 * 4]) = v;
        }
        __syncthreads();

        const int r0 = q * 16;
        float accA[16], accB[16];
#pragma unroll
        for (int r = 0; r < 16; ++r) { accA[r] = 0.f; accB[r] = 0.f; }

        for (int k4 = 0; k4 < 16; ++k4) {
            const float2 wa0 = *reinterpret_cast<const float2*>(&sWaT[lane * 66 + k4 * 4]);
            const float2 wa1 = *reinterpret_cast<const float2*>(&sWaT[lane * 66 + k4 * 4 + 2]);
            const float2 wb0 = *reinterpret_cast<const float2*>(&sWbT[lane * 66 + k4 * 4]);
            const float2 wb1 = *reinterpret_cast<const float2*>(&sWbT[lane * 66 + k4 * 4 + 2]);
#pragma unroll
            for (int r = 0; r < 16; ++r) {
                const float4 xv = *reinterpret_cast<const float4*>(&sX[(r0 + r) * 68 + k4 * 4]);
                accA[r] = fmaf(xv.x, wa0.x, accA[r]);
                accA[r] = fmaf(xv.y, wa0.y, accA[r]);
                accA[r] = fmaf(xv.z, wa1.x, accA[r]);
                accA[r] = fmaf(xv.w, wa1.y, accA[r]);
                accB[r] = fmaf(xv.x, wb0.x, accB[r]);
                accB[r] = fmaf(xv.y, wb0.y, accB[r]);
                accB[r] = fmaf(xv.z, wb1.x, accB[r]);
                accB[r] = fmaf(xv.w, wb1.y, accB[r]);
            }
        }
#pragma unroll
        for (int r = 0; r < 16; ++r) {
            int row = rowbase + r0 + r;
            if (row < n) {
                Ya[(size_t)row * 64 + lane] = accA[r];
                Yb[(size_t)row * 64 + lane] = accB[r];
            }
        }
    }
}

// ---------------------------------------------------------------------------
// p-pass: one thread per row, dual dot product in-register.
// ---------------------------------------------------------------------------
__global__ void ppass_kernel(const float* __restrict__ m0, const float* __restrict__ m1,
                             const float* __restrict__ sm, const float* __restrict__ tm,
                             const float* __restrict__ a0, const float* __restrict__ a1,
                             const float* __restrict__ ans,
                             float* __restrict__ pl0, float* __restrict__ pr0,
                             float* __restrict__ pl1, float* __restrict__ pr1,
                             float* __restrict__ pls, float* __restrict__ prs,
                             float* __restrict__ plt, float* __restrict__ prt,
                             int N0, int N1)
{
    int g = blockIdx.x * blockDim.x + threadIdx.x;
    if (g >= 2 * (N0 + N1)) return;
    const float* M; const float* a; float* pL; float* pR; int r;
    if (g < N0)                { M = m0; a = a0;  pL = pl0; pR = pr0; r = g; }
    else if (g < N0 + N1)      { M = m1; a = a1;  pL = pl1; pR = pr1; r = g - N0; }
    else if (g < N0 + 2 * N1)  { M = sm; a = ans; pL = pls; pR = prs; r = g - N0 - N1; }
    else                       { M = tm; a = ans; pL = plt; pR = prt; r = g - N0 - 2 * N1; }

    const float4* row = reinterpret_cast<const float4*>(M + (size_t)r * 64);
    float sl = 0.f, sr = 0.f;
#pragma unroll
    for (int k4 = 0; k4 < 16; ++k4) {
        float4 xv = row[k4];
        float4 al = *reinterpret_cast<const float4*>(a + k4 * 4);
        float4 ar = *reinterpret_cast<const float4*>(a + 64 + k4 * 4);
        sl = fmaf(xv.x, al.x, sl); sl = fmaf(xv.y, al.y, sl);
        sl = fmaf(xv.z, al.z, sl); sl = fmaf(xv.w, al.w, sl);
        sr = fmaf(xv.x, ar.x, sr); sr = fmaf(xv.y, ar.y, sr);
        sr = fmaf(xv.z, ar.z, sr); sr = fmaf(xv.w, ar.w, sr);
    }
    pL[r] = sl;
    pR[r] = sr;
}

// ---------------------------------------------------------------------------
// Edge-list descriptor for fused count/fill over 4 lists.
// ---------------------------------------------------------------------------
struct EdgeLists {
    const int* keys[4];
    const int* vals[4];
    int* cur[4];
    int E[4];
    int blk[5];   // cumulative block offsets per list (1024 edges/block)
};

__device__ __forceinline__ int list_of(const EdgeLists& d, int b)
{
    return (b >= d.blk[2]) ? ((b >= d.blk[3]) ? 3 : 2) : ((b >= d.blk[1]) ? 1 : 0);
}

// 4 edges/thread histogram (int atomics).
__global__ void count4_kernel(EdgeLists d)
{
    int b = blockIdx.x;
    int l = list_of(d, b);
    int base = (b - d.blk[l]) * 1024 + threadIdx.x * 4;
    int E = d.E[l];
    if (base >= E) return;
    int* cur = d.cur[l];
    if (base + 3 < E) {
        int4 k4 = *reinterpret_cast<const int4*>(d.keys[l] + base);
        atomicAdd(&cur[k4.x], 1);
        atomicAdd(&cur[k4.y], 1);
        atomicAdd(&cur[k4.z], 1);
        atomicAdd(&cur[k4.w], 1);
    } else {
        for (int u = base; u < E; ++u) atomicAdd(&cur[d.keys[l][u]], 1);
    }
}

// 4 edges/thread CSR fill: csr[pos] = j (payload only; e recomputed in gather).
__global__ void fill4_kernel(EdgeLists d, int* __restrict__ csr)
{
    int b = blockIdx.x;
    int l = list_of(d, b);
    int base = (b - d.blk[l]) * 1024 + threadIdx.x * 4;
    int E = d.E[l];
    if (base >= E) return;
    int* cur = d.cur[l];
    if (base + 3 < E) {
        int4 k4 = *reinterpret_cast<const int4*>(d.keys[l] + base);
        int4 v4 = *reinterpret_cast<const int4*>(d.vals[l] + base);
        int p0 = atomicAdd(&cur[k4.x], 1);
        int p1 = atomicAdd(&cur[k4.y], 1);
        int p2 = atomicAdd(&cur[k4.z], 1);
        int p3 = atomicAdd(&cur[k4.w], 1);
        __builtin_nontemporal_store(v4.x, csr + p0);
        __builtin_nontemporal_store(v4.y, csr + p1);
        __builtin_nontemporal_store(v4.z, csr + p2);
        __builtin_nontemporal_store(v4.w, csr + p3);
    } else {
        for (int u = base; u < E; ++u) {
            int pos = atomicAdd(&cur[d.keys[l][u]], 1);
            __builtin_nontemporal_store(d.vals[l][u], csr + pos);
        }
    }
}

// ---------------------------------------------------------------------------
// 3-kernel global exclusive scan over cnt[0..n), chunk = 2048/block.
// ---------------------------------------------------------------------------
#define SCAN_CHUNK 2048

__global__ void scan_partials(const int* __restrict__ cnt, int* __restrict__ part, int n)
{
    __shared__ int tsum[256];
    int b = blockIdx.x, t = threadIdx.x;
    int base = b * SCAN_CHUNK + t * 8;
    int s = 0;
#pragma unroll
    for (int u = 0; u < 8; ++u) { int idx = base + u; if (idx < n) s += cnt[idx]; }
    tsum[t] = s;
    __syncthreads();
    for (int off = 128; off; off >>= 1) {
        if (t < off) tsum[t] += tsum[t + off];
        __syncthreads();
    }
    if (t == 0) part[b] = tsum[0];
}

__global__ void scan_small(int* __restrict__ part, int n)
{
    __shared__ int sh[256];
    int t = threadIdx.x;
    sh[t] = (t < n) ? part[t] : 0;
    __syncthreads();
    for (int off = 1; off < 256; off <<= 1) {
        int x = (t >= off) ? sh[t - off] : 0;
        __syncthreads();
        sh[t] += x;
        __syncthreads();
    }
    if (t < n) part[t] = (t == 0) ? 0 : sh[t - 1];
}

__global__ void scan_apply(int* __restrict__ cnt, const int* __restrict__ part, int n)
{
    __shared__ int tsum[256];
    int b = blockIdx.x, t = threadIdx.x;
    int base = b * SCAN_CHUNK + t * 8;
    int v[8];
    int s = 0;
#pragma unroll
    for (int u = 0; u < 8; ++u) {
        int idx = base + u;
        v[u] = (idx < n) ? cnt[idx] : 0;
        s += v[u];
    }
    tsum[t] = s;
    __syncthreads();
    for (int off = 1; off < 256; off <<= 1) {
        int x = (t >= off) ? tsum[t - off] : 0;
        __syncthreads();
        tsum[t] += x;
        __syncthreads();
    }
    int pre = part[b] + ((t == 0) ? 0 : tsum[t - 1]);
#pragma unroll
    for (int u = 0; u < 8; ++u) {
        int idx = base + u;
        if (idx < n) cnt[idx] = pre;
        pre += v[u];
    }
}

// ---------------------------------------------------------------------------
// Fused dual pull-gather with on-the-fly scores:
//   out[r] = (1/denA) * sum e_A * MA[j]  +  (1/denB) * sum e_B * MB[j]
//   e = lrelu(pl[row] + pr[j]) computed per edge; den = sum e per row.
// 4 edge-groups of 16 lanes; lane owns 4 channels (float4).
// ---------------------------------------------------------------------------
struct GDesc {
    const int* curA; const float* MA; const float* plA; const float* prA; int baseA;
    const int* curB; const float* MB; const float* plB; const float* prB; int baseB;
    float* out; int n;
};

__global__ void gather2_kernel(GDesc gd, const int* __restrict__ csr)
{
    const int lane = threadIdx.x & 63;
    const int g = lane >> 4;
    const int c4 = (lane & 15) << 2;
    int wave = (int)((blockIdx.x * blockDim.x + threadIdx.x) >> 6);
    int nw = (int)((gridDim.x * blockDim.x) >> 6);

    for (int r = wave; r < gd.n; r += nw) {
        float4 accA = make_float4(0.f, 0.f, 0.f, 0.f);
        float4 accB = make_float4(0.f, 0.f, 0.f, 0.f);
        float seA = 0.f, seB = 0.f;

        {
            const float pl = gd.plA[r];
            int p0 = (r == 0) ? gd.baseA : gd.curA[r - 1];
            int p1 = gd.curA[r];
#pragma unroll 4
            for (int p = p0; p < p1; p += 4) {
                int idx = p + g;
                bool ok = idx < p1;
                int j = ok ? __builtin_nontemporal_load(csr + idx) : 0;
                float e = ok ? lrelu(pl + gd.prA[j]) : 0.f;
                seA += e;
                const float4 row = *reinterpret_cast<const float4*>(gd.MA + (size_t)j * 64 + c4);
                accA.x = fmaf(e, row.x, accA.x);
                accA.y = fmaf(e, row.y, accA.y);
                accA.z = fmaf(e, row.z, accA.z);
                accA.w = fmaf(e, row.w, accA.w);
            }
        }
        {
            const float pl = gd.plB[r];
            int p0 = (r == 0) ? gd.baseB : gd.curB[r - 1];
            int p1 = gd.curB[r];
#pragma unroll 4
            for (int p = p0; p < p1; p += 4) {
                int idx = p + g;
                bool ok = idx < p1;
                int j = ok ? __builtin_nontemporal_load(csr + idx) : 0;
                float e = ok ? lrelu(pl + gd.prB[j]) : 0.f;
                seB += e;
                const float4 row = *reinterpret_cast<const float4*>(gd.MB + (size_t)j * 64 + c4);
                accB.x = fmaf(e, row.x, accB.x);
                accB.y = fmaf(e, row.y, accB.y);
                accB.z = fmaf(e, row.z, accB.z);
                accB.w = fmaf(e, row.w, accB.w);
            }
        }

        seA += __shfl_xor(seA, 16, 64); seA += __shfl_xor(seA, 32, 64);
        seB += __shfl_xor(seB, 16, 64); seB += __shfl_xor(seB, 32, 64);
        float rA = 1.f / ((seA == 0.f) ? 1.f : seA);
        float rB = 1.f / ((seB == 0.f) ? 1.f : seB);

        float4 part;
        part.x = accA.x * rA + accB.x * rB;
        part.y = accA.y * rA + accB.y * rB;
        part.z = accA.z * rA + accB.z * rB;
        part.w = accA.w * rA + accB.w * rB;
        part.x += __shfl_xor(part.x, 16, 64); part.x += __shfl_xor(part.x, 32, 64);
        part.y += __shfl_xor(part.y, 16, 64); part.y += __shfl_xor(part.y, 32, 64);
        part.z += __shfl_xor(part.z, 16, 64); part.z += __shfl_xor(part.z, 32, 64);
        part.w += __shfl_xor(part.w, 16, 64); part.w += __shfl_xor(part.w, 32, 64);

        if (g == 0) *reinterpret_cast<float4*>(gd.out + (size_t)r * 64 + c4) = part;
    }
}

extern "C" void kernel_launch(void* const* d_in, const int* in_sizes, int n_in,
                              void* d_out, int out_size, void* d_ws, size_t ws_size,
                              hipStream_t stream)
{
    const float* x0  = (const float*)d_in[0];
    const float* x1  = (const float*)d_in[1];
    const float* x2  = (const float*)d_in[2];
    const float* x3  = (const float*)d_in[3];
    const float* x4  = (const float*)d_in[4];
    const int*   adj0 = (const int*)d_in[5];
    const int*   adj1 = (const int*)d_in[6];
    const int*   inct = (const int*)d_in[7];
    const int*   incs = (const int*)d_in[8];
    const float* W0  = (const float*)d_in[9];
    const float* a0  = (const float*)d_in[10];
    const float* W1  = (const float*)d_in[11];
    const float* a1  = (const float*)d_in[12];
    const float* Ws  = (const float*)d_in[13];
    const float* Wt  = (const float*)d_in[14];
    const float* ans = (const float*)d_in[15];

    const int N0  = in_sizes[0] / CDIM;      // 50000
    const int N1  = in_sizes[1] / CDIM;      // 100000
    const int NP  = in_sizes[2];             // passthrough flat size
    const int E0  = in_sizes[5] / 2;         // 800000
    const int E1  = in_sizes[6] / 2;         // 1600000
    const int E01 = in_sizes[7];             // 200000

    float* out0 = (float*)d_out;
    float* out1 = out0 + (size_t)N0 * CDIM;
    float* outp = out1 + (size_t)N1 * CDIM;

    // ---- workspace layout ----
    char* w = (char*)d_ws;
    size_t off = 0;
    float* m0  = (float*)(w + off); off += (size_t)N0 * CDIM * 4;
    float* m1  = (float*)(w + off); off += (size_t)N1 * CDIM * 4;
    float* sm  = (float*)(w + off); off += (size_t)N1 * CDIM * 4;
    float* tm  = (float*)(w + off); off += (size_t)N0 * CDIM * 4;
    float* pl0 = (float*)(w + off); off += (size_t)N0 * 4;
    float* pr0 = (float*)(w + off); off += (size_t)N0 * 4;
    float* pl1 = (float*)(w + off); off += (size_t)N1 * 4;
    float* pr1 = (float*)(w + off); off += (size_t)N1 * 4;
    float* pls = (float*)(w + off); off += (size_t)N1 * 4;   // p_s = sm @ a_ns[:C]
    float* prs = (float*)(w + off); off += (size_t)N1 * 4;   // scratch
    float* plt = (float*)(w + off); off += (size_t)N0 * 4;   // scratch
    float* prt = (float*)(w + off); off += (size_t)N0 * 4;   // p_t = tm @ a_ns[C:]
    int* curAll = (int*)(w + off);
    int* cur0 = curAll;            // N0
    int* cur1 = cur0 + N0;         // N1
    int* curT = cur1 + N1;         // N0
    int* curS = curT + N0;         // N1
    const int Ntot = N0 + N1 + N0 + N1;
    off += (size_t)Ntot * 4;
    int* part = (int*)(w + off); off += 1024 * 4;
    int* csrAll = (int*)(w + off); off += ((size_t)E0 + E1 + 2 * (size_t)E01) * 4;
    (void)ws_size; (void)n_in; (void)out_size;

    const int base0 = 0;
    const int base1 = E0;
    const int baseT = E0 + E1;
    const int baseS = E0 + E1 + E01;

    dim3 blk(256);

    // ---- edge-list descriptors (1024 edges per block) ----
    EdgeLists d;
    d.keys[0] = adj0;      d.vals[0] = adj0 + E0; d.cur[0] = cur0; d.E[0] = E0;
    d.keys[1] = adj1;      d.vals[1] = adj1 + E1; d.cur[1] = cur1; d.E[1] = E1;
    d.keys[2] = inct;      d.vals[2] = incs;      d.cur[2] = curT; d.E[2] = E01;
    d.keys[3] = incs;      d.vals[3] = inct;      d.cur[3] = curS; d.E[3] = E01;
    d.blk[0] = 0;
    for (int l = 0; l < 4; ++l) d.blk[l + 1] = d.blk[l] + (d.E[l] + 1023) / 1024;
    const int nEdgeBlk = d.blk[4];

    // ---- CSR build: count -> global scan -> fill (independent of GEMM) ----
    hipMemsetAsync(curAll, 0, (size_t)Ntot * 4, stream);
    count4_kernel<<<nEdgeBlk, blk, 0, stream>>>(d);

    int nCh = (Ntot + SCAN_CHUNK - 1) / SCAN_CHUNK;
    scan_partials<<<nCh, blk, 0, stream>>>(curAll, part, Ntot);
    scan_small<<<1, blk, 0, stream>>>(part, nCh);
    scan_apply<<<nCh, blk, 0, stream>>>(curAll, part, Ntot);

    fill4_kernel<<<nEdgeBlk, blk, 0, stream>>>(d, csrAll);

    // ---- dense projections + p-pass ----
    gemm64x2_tiled<<<(N0 + 63) / 64, blk, 0, stream>>>(x0, W0, m0, Wt, tm, N0);
    gemm64x2_tiled<<<(N1 + 63) / 64, blk, 0, stream>>>(x1, W1, m1, Ws, sm, N1);
    ppass_kernel<<<(2 * (N0 + N1) + 255) / 256, blk, 0, stream>>>(
        m0, m1, sm, tm, a0, a1, ans,
        pl0, pr0, pl1, pr1, pls, prs, plt, prt, N0, N1);

    // ---- fused pull gathers (scores on the fly) ----
    GDesc g0 = { cur0, m0, pl0, pr0, base0,
                 curT, sm, prt, pls, baseT,
                 out0, N0 };
    GDesc g1 = { cur1, m1, pl1, pr1, base1,
                 curS, tm, pls, prt, baseS,
                 out1, N1 };
    gather2_kernel<<<2048, blk, 0, stream>>>(g0, csrAll);
    gather2_kernel<<<2048, blk, 0, stream>>>(g1, csrAll);

    // ---- passthroughs x_2, x_3, x_4 ----
    hipMemcpyAsync(outp,          x2, (size_t)NP * sizeof(float), hipMemcpyDeviceToDevice, stream);
    hipMemcpyAsync(outp + NP,     x3, (size_t)NP * sizeof(float), hipMemcpyDeviceToDevice, stream);
    hipMemcpyAsync(outp + 2 * NP, x4, (size_t)NP * sizeof(float), hipMemcpyDeviceToDevice, stream);
}

// Round 7
// 532.706 us; speedup vs baseline: 1.1812x; 1.1812x over previous
//
#include <hip/hip_runtime.h>

#define CDIM 64
#define SLOPE 0.2f
#define NBANDS 8

__device__ __forceinline__ float lrelu(float v) { return v > 0.f ? v : SLOPE * v; }

// ---------------------------------------------------------------------------
// Tiled dual GEMM, shuffle-free: Ya = X@Wa, Yb = X@Wb.
// ---------------------------------------------------------------------------
__global__ void gemm64x2_tiled(const float* __restrict__ X,
                               const float* __restrict__ Wa, float* __restrict__ Ya,
                               const float* __restrict__ Wb, float* __restrict__ Yb,
                               int n)
{
    __shared__ float sX[64 * 68];
    __shared__ float sWaT[64 * 66];
    __shared__ float sWbT[64 * 66];
    const int tid = threadIdx.x;
    const int lane = tid & 63;
    const int q = tid >> 6;

    for (int idx = tid; idx < 4096; idx += 256) {
        int k = idx >> 6, c = idx & 63;
        sWaT[c * 66 + k] = Wa[idx];
        sWbT[c * 66 + k] = Wb[idx];
    }

    const int ntiles = (n + 63) >> 6;
    for (int tile = blockIdx.x; tile < ntiles; tile += gridDim.x) {
        const int rowbase = tile << 6;
        __syncthreads();
#pragma unroll
        for (int i = 0; i < 4; ++i) {
            int f = tid + i * 256;
            int r = f >> 4, k4 = f & 15;
            int row = rowbase + r;
            float4 v = make_float4(0.f, 0.f, 0.f, 0.f);
            if (row < n) v = *reinterpret_cast<const float4*>(X + (size_t)row * 64 + k4 * 4);
            *reinterpret_cast<float4*>(&sX[r * 68 + k4 * 4]) = v;
        }
        __syncthreads();

        const int r0 = q * 16;
        float accA[16], accB[16];
#pragma unroll
        for (int r = 0; r < 16; ++r) { accA[r] = 0.f; accB[r] = 0.f; }

        for (int k4 = 0; k4 < 16; ++k4) {
            const float2 wa0 = *reinterpret_cast<const float2*>(&sWaT[lane * 66 + k4 * 4]);
            const float2 wa1 = *reinterpret_cast<const float2*>(&sWaT[lane * 66 + k4 * 4 + 2]);
            const float2 wb0 = *reinterpret_cast<const float2*>(&sWbT[lane * 66 + k4 * 4]);
            const float2 wb1 = *reinterpret_cast<const float2*>(&sWbT[lane * 66 + k4 * 4 + 2]);
#pragma unroll
            for (int r = 0; r < 16; ++r) {
                const float4 xv = *reinterpret_cast<const float4*>(&sX[(r0 + r) * 68 + k4 * 4]);
                accA[r] = fmaf(xv.x, wa0.x, accA[r]);
                accA[r] = fmaf(xv.y, wa0.y, accA[r]);
                accA[r] = fmaf(xv.z, wa1.x, accA[r]);
                accA[r] = fmaf(xv.w, wa1.y, accA[r]);
                accB[r] = fmaf(xv.x, wb0.x, accB[r]);
                accB[r] = fmaf(xv.y, wb0.y, accB[r]);
                accB[r] = fmaf(xv.z, wb1.x, accB[r]);
                accB[r] = fmaf(xv.w, wb1.y, accB[r]);
            }
        }
#pragma unroll
        for (int r = 0; r < 16; ++r) {
            int row = rowbase + r0 + r;
            if (row < n) {
                Ya[(size_t)row * 64 + lane] = accA[r];
                Yb[(size_t)row * 64 + lane] = accB[r];
            }
        }
    }
}

// ---------------------------------------------------------------------------
// p-pass: one thread per row, dual dot product in-register.
// ---------------------------------------------------------------------------
__global__ void ppass_kernel(const float* __restrict__ m0, const float* __restrict__ m1,
                             const float* __restrict__ sm, const float* __restrict__ tm,
                             const float* __restrict__ a0, const float* __restrict__ a1,
                             const float* __restrict__ ans,
                             float* __restrict__ pl0, float* __restrict__ pr0,
                             float* __restrict__ pl1, float* __restrict__ pr1,
                             float* __restrict__ pls, float* __restrict__ prs,
                             float* __restrict__ plt, float* __restrict__ prt,
                             int N0, int N1)
{
    int g = blockIdx.x * blockDim.x + threadIdx.x;
    if (g >= 2 * (N0 + N1)) return;
    const float* M; const float* a; float* pL; float* pR; int r;
    if (g < N0)                { M = m0; a = a0;  pL = pl0; pR = pr0; r = g; }
    else if (g < N0 + N1)      { M = m1; a = a1;  pL = pl1; pR = pr1; r = g - N0; }
    else if (g < N0 + 2 * N1)  { M = sm; a = ans; pL = pls; pR = prs; r = g - N0 - N1; }
    else                       { M = tm; a = ans; pL = plt; pR = prt; r = g - N0 - 2 * N1; }

    const float4* row = reinterpret_cast<const float4*>(M + (size_t)r * 64);
    float sl = 0.f, sr = 0.f;
#pragma unroll
    for (int k4 = 0; k4 < 16; ++k4) {
        float4 xv = row[k4];
        float4 al = *reinterpret_cast<const float4*>(a + k4 * 4);
        float4 ar = *reinterpret_cast<const float4*>(a + 64 + k4 * 4);
        sl = fmaf(xv.x, al.x, sl); sl = fmaf(xv.y, al.y, sl);
        sl = fmaf(xv.z, al.z, sl); sl = fmaf(xv.w, al.w, sl);
        sr = fmaf(xv.x, ar.x, sr); sr = fmaf(xv.y, ar.y, sr);
        sr = fmaf(xv.z, ar.z, sr); sr = fmaf(xv.w, ar.w, sr);
    }
    pL[r] = sl;
    pR[r] = sr;
}

// ---------------------------------------------------------------------------
// Edge-list descriptor for fused count/fill over 4 lists.
// ---------------------------------------------------------------------------
struct EdgeLists {
    const int* keys[4];
    const int* vals[4];
    int* cur[4];
    int E[4];
    int N[4];     // row count per list (key domain size)
    int blk[5];   // cumulative block offsets per list (1024 edges/block)
};

__device__ __forceinline__ int list_of(const EdgeLists& d, int b)
{
    return (b >= d.blk[2]) ? ((b >= d.blk[3]) ? 3 : 2) : ((b >= d.blk[1]) ? 1 : 0);
}

// 4 edges/thread histogram (int atomics).
__global__ void count4_kernel(EdgeLists d)
{
    int b = blockIdx.x;
    int l = list_of(d, b);
    int base = (b - d.blk[l]) * 1024 + threadIdx.x * 4;
    int E = d.E[l];
    if (base >= E) return;
    int* cur = d.cur[l];
    if (base + 3 < E) {
        int4 k4 = *reinterpret_cast<const int4*>(d.keys[l] + base);
        atomicAdd(&cur[k4.x], 1);
        atomicAdd(&cur[k4.y], 1);
        atomicAdd(&cur[k4.z], 1);
        atomicAdd(&cur[k4.w], 1);
    } else {
        for (int u = base; u < E; ++u) atomicAdd(&cur[d.keys[l][u]], 1);
    }
}

// ---------------------------------------------------------------------------
// Banded CSR fill. blockIdx.y = band. Band b handles keys in
// [b*N/NBANDS, (b+1)*N/NBANDS): its csr destination window is small enough
// to stay L2-resident, so the ~deg writes to each 64B line combine and the
// line writes back to HBM once (vs once per edge when unbanded).
// ---------------------------------------------------------------------------
__global__ void fill_banded(EdgeLists d, int* __restrict__ csr)
{
    int b = blockIdx.x;
    int l = list_of(d, b);
    int base = (b - d.blk[l]) * 1024 + threadIdx.x * 4;
    int E = d.E[l];
    if (base >= E) return;
    const int Nl = d.N[l];
    const int band = blockIdx.y;
    const int lo = (int)((size_t)band * Nl / NBANDS);
    const int hi = (int)((size_t)(band + 1) * Nl / NBANDS);
    int* cur = d.cur[l];

    if (base + 3 < E) {
        int4 k4 = *reinterpret_cast<const int4*>(d.keys[l] + base);
        if (k4.x >= lo && k4.x < hi) {
            int pos = atomicAdd(&cur[k4.x], 1);
            csr[pos] = d.vals[l][base + 0];
        }
        if (k4.y >= lo && k4.y < hi) {
            int pos = atomicAdd(&cur[k4.y], 1);
            csr[pos] = d.vals[l][base + 1];
        }
        if (k4.z >= lo && k4.z < hi) {
            int pos = atomicAdd(&cur[k4.z], 1);
            csr[pos] = d.vals[l][base + 2];
        }
        if (k4.w >= lo && k4.w < hi) {
            int pos = atomicAdd(&cur[k4.w], 1);
            csr[pos] = d.vals[l][base + 3];
        }
    } else {
        for (int u = base; u < E; ++u) {
            int k = d.keys[l][u];
            if (k >= lo && k < hi) {
                int pos = atomicAdd(&cur[k], 1);
                csr[pos] = d.vals[l][u];
            }
        }
    }
}

// ---------------------------------------------------------------------------
// 3-kernel global exclusive scan over cnt[0..n), chunk = 2048/block.
// ---------------------------------------------------------------------------
#define SCAN_CHUNK 2048

__global__ void scan_partials(const int* __restrict__ cnt, int* __restrict__ part, int n)
{
    __shared__ int tsum[256];
    int b = blockIdx.x, t = threadIdx.x;
    int base = b * SCAN_CHUNK + t * 8;
    int s = 0;
#pragma unroll
    for (int u = 0; u < 8; ++u) { int idx = base + u; if (idx < n) s += cnt[idx]; }
    tsum[t] = s;
    __syncthreads();
    for (int off = 128; off; off >>= 1) {
        if (t < off) tsum[t] += tsum[t + off];
        __syncthreads();
    }
    if (t == 0) part[b] = tsum[0];
}

__global__ void scan_small(int* __restrict__ part, int n)
{
    __shared__ int sh[256];
    int t = threadIdx.x;
    sh[t] = (t < n) ? part[t] : 0;
    __syncthreads();
    for (int off = 1; off < 256; off <<= 1) {
        int x = (t >= off) ? sh[t - off] : 0;
        __syncthreads();
        sh[t] += x;
        __syncthreads();
    }
    if (t < n) part[t] = (t == 0) ? 0 : sh[t - 1];
}

__global__ void scan_apply(int* __restrict__ cnt, const int* __restrict__ part, int n)
{
    __shared__ int tsum[256];
    int b = blockIdx.x, t = threadIdx.x;
    int base = b * SCAN_CHUNK + t * 8;
    int v[8];
    int s = 0;
#pragma unroll
    for (int u = 0; u < 8; ++u) {
        int idx = base + u;
        v[u] = (idx < n) ? cnt[idx] : 0;
        s += v[u];
    }
    tsum[t] = s;
    __syncthreads();
    for (int off = 1; off < 256; off <<= 1) {
        int x = (t >= off) ? tsum[t - off] : 0;
        __syncthreads();
        tsum[t] += x;
        __syncthreads();
    }
    int pre = part[b] + ((t == 0) ? 0 : tsum[t - 1]);
#pragma unroll
    for (int u = 0; u < 8; ++u) {
        int idx = base + u;
        if (idx < n) cnt[idx] = pre;
        pre += v[u];
    }
}

// ---------------------------------------------------------------------------
// Fused dual pull-gather with on-the-fly scores:
//   out[r] = (1/denA) * sum e_A * MA[j]  +  (1/denB) * sum e_B * MB[j]
//   e = lrelu(pl[row] + pr[j]); den = sum e per row.
// ---------------------------------------------------------------------------
struct GDesc {
    const int* curA; const float* MA; const float* plA; const float* prA; int baseA;
    const int* curB; const float* MB; const float* plB; const float* prB; int baseB;
    float* out; int n;
};

__global__ void gather2_kernel(GDesc gd, const int* __restrict__ csr)
{
    const int lane = threadIdx.x & 63;
    const int g = lane >> 4;
    const int c4 = (lane & 15) << 2;
    int wave = (int)((blockIdx.x * blockDim.x + threadIdx.x) >> 6);
    int nw = (int)((gridDim.x * blockDim.x) >> 6);

    for (int r = wave; r < gd.n; r += nw) {
        float4 accA = make_float4(0.f, 0.f, 0.f, 0.f);
        float4 accB = make_float4(0.f, 0.f, 0.f, 0.f);
        float seA = 0.f, seB = 0.f;

        {
            const float pl = gd.plA[r];
            int p0 = (r == 0) ? gd.baseA : gd.curA[r - 1];
            int p1 = gd.curA[r];
#pragma unroll 4
            for (int p = p0; p < p1; p += 4) {
                int idx = p + g;
                bool ok = idx < p1;
                int j = ok ? __builtin_nontemporal_load(csr + idx) : 0;
                float e = ok ? lrelu(pl + gd.prA[j]) : 0.f;
                seA += e;
                const float4 row = *reinterpret_cast<const float4*>(gd.MA + (size_t)j * 64 + c4);
                accA.x = fmaf(e, row.x, accA.x);
                accA.y = fmaf(e, row.y, accA.y);
                accA.z = fmaf(e, row.z, accA.z);
                accA.w = fmaf(e, row.w, accA.w);
            }
        }
        {
            const float pl = gd.plB[r];
            int p0 = (r == 0) ? gd.baseB : gd.curB[r - 1];
            int p1 = gd.curB[r];
#pragma unroll 4
            for (int p = p0; p < p1; p += 4) {
                int idx = p + g;
                bool ok = idx < p1;
                int j = ok ? __builtin_nontemporal_load(csr + idx) : 0;
                float e = ok ? lrelu(pl + gd.prB[j]) : 0.f;
                seB += e;
                const float4 row = *reinterpret_cast<const float4*>(gd.MB + (size_t)j * 64 + c4);
                accB.x = fmaf(e, row.x, accB.x);
                accB.y = fmaf(e, row.y, accB.y);
                accB.z = fmaf(e, row.z, accB.z);
                accB.w = fmaf(e, row.w, accB.w);
            }
        }

        seA += __shfl_xor(seA, 16, 64); seA += __shfl_xor(seA, 32, 64);
        seB += __shfl_xor(seB, 16, 64); seB += __shfl_xor(seB, 32, 64);
        float rA = 1.f / ((seA == 0.f) ? 1.f : seA);
        float rB = 1.f / ((seB == 0.f) ? 1.f : seB);

        float4 part;
        part.x = accA.x * rA + accB.x * rB;
        part.y = accA.y * rA + accB.y * rB;
        part.z = accA.z * rA + accB.z * rB;
        part.w = accA.w * rA + accB.w * rB;
        part.x += __shfl_xor(part.x, 16, 64); part.x += __shfl_xor(part.x, 32, 64);
        part.y += __shfl_xor(part.y, 16, 64); part.y += __shfl_xor(part.y, 32, 64);
        part.z += __shfl_xor(part.z, 16, 64); part.z += __shfl_xor(part.z, 32, 64);
        part.w += __shfl_xor(part.w, 16, 64); part.w += __shfl_xor(part.w, 32, 64);

        if (g == 0) *reinterpret_cast<float4*>(gd.out + (size_t)r * 64 + c4) = part;
    }
}

extern "C" void kernel_launch(void* const* d_in, const int* in_sizes, int n_in,
                              void* d_out, int out_size, void* d_ws, size_t ws_size,
                              hipStream_t stream)
{
    const float* x0  = (const float*)d_in[0];
    const float* x1  = (const float*)d_in[1];
    const float* x2  = (const float*)d_in[2];
    const float* x3  = (const float*)d_in[3];
    const float* x4  = (const float*)d_in[4];
    const int*   adj0 = (const int*)d_in[5];
    const int*   adj1 = (const int*)d_in[6];
    const int*   inct = (const int*)d_in[7];
    const int*   incs = (const int*)d_in[8];
    const float* W0  = (const float*)d_in[9];
    const float* a0  = (const float*)d_in[10];
    const float* W1  = (const float*)d_in[11];
    const float* a1  = (const float*)d_in[12];
    const float* Ws  = (const float*)d_in[13];
    const float* Wt  = (const float*)d_in[14];
    const float* ans = (const float*)d_in[15];

    const int N0  = in_sizes[0] / CDIM;      // 50000
    const int N1  = in_sizes[1] / CDIM;      // 100000
    const int NP  = in_sizes[2];             // passthrough flat size
    const int E0  = in_sizes[5] / 2;         // 800000
    const int E1  = in_sizes[6] / 2;         // 1600000
    const int E01 = in_sizes[7];             // 200000

    float* out0 = (float*)d_out;
    float* out1 = out0 + (size_t)N0 * CDIM;
    float* outp = out1 + (size_t)N1 * CDIM;

    // ---- workspace layout ----
    char* w = (char*)d_ws;
    size_t off = 0;
    float* m0  = (float*)(w + off); off += (size_t)N0 * CDIM * 4;
    float* m1  = (float*)(w + off); off += (size_t)N1 * CDIM * 4;
    float* sm  = (float*)(w + off); off += (size_t)N1 * CDIM * 4;
    float* tm  = (float*)(w + off); off += (size_t)N0 * CDIM * 4;
    float* pl0 = (float*)(w + off); off += (size_t)N0 * 4;
    float* pr0 = (float*)(w + off); off += (size_t)N0 * 4;
    float* pl1 = (float*)(w + off); off += (size_t)N1 * 4;
    float* pr1 = (float*)(w + off); off += (size_t)N1 * 4;
    float* pls = (float*)(w + off); off += (size_t)N1 * 4;   // p_s = sm @ a_ns[:C]
    float* prs = (float*)(w + off); off += (size_t)N1 * 4;   // scratch
    float* plt = (float*)(w + off); off += (size_t)N0 * 4;   // scratch
    float* prt = (float*)(w + off); off += (size_t)N0 * 4;   // p_t = tm @ a_ns[C:]
    int* curAll = (int*)(w + off);
    int* cur0 = curAll;            // N0
    int* cur1 = cur0 + N0;         // N1
    int* curT = cur1 + N1;         // N0
    int* curS = curT + N0;         // N1
    const int Ntot = N0 + N1 + N0 + N1;
    off += (size_t)Ntot * 4;
    int* part = (int*)(w + off); off += 1024 * 4;
    int* csrAll = (int*)(w + off); off += ((size_t)E0 + E1 + 2 * (size_t)E01) * 4;
    (void)ws_size; (void)n_in; (void)out_size;

    const int base0 = 0;
    const int base1 = E0;
    const int baseT = E0 + E1;
    const int baseS = E0 + E1 + E01;

    dim3 blk(256);

    // ---- edge-list descriptors (1024 edges per block) ----
    EdgeLists d;
    d.keys[0] = adj0;      d.vals[0] = adj0 + E0; d.cur[0] = cur0; d.E[0] = E0;  d.N[0] = N0;
    d.keys[1] = adj1;      d.vals[1] = adj1 + E1; d.cur[1] = cur1; d.E[1] = E1;  d.N[1] = N1;
    d.keys[2] = inct;      d.vals[2] = incs;      d.cur[2] = curT; d.E[2] = E01; d.N[2] = N0;
    d.keys[3] = incs;      d.vals[3] = inct;      d.cur[3] = curS; d.E[3] = E01; d.N[3] = N1;
    d.blk[0] = 0;
    for (int l = 0; l < 4; ++l) d.blk[l + 1] = d.blk[l] + (d.E[l] + 1023) / 1024;
    const int nEdgeBlk = d.blk[4];

    // ---- CSR build: count -> global scan -> banded fill ----
    hipMemsetAsync(curAll, 0, (size_t)Ntot * 4, stream);
    count4_kernel<<<nEdgeBlk, blk, 0, stream>>>(d);

    int nCh = (Ntot + SCAN_CHUNK - 1) / SCAN_CHUNK;
    scan_partials<<<nCh, blk, 0, stream>>>(curAll, part, Ntot);
    scan_small<<<1, blk, 0, stream>>>(part, nCh);
    scan_apply<<<nCh, blk, 0, stream>>>(curAll, part, Ntot);

    fill_banded<<<dim3(nEdgeBlk, NBANDS), blk, 0, stream>>>(d, csrAll);

    // ---- dense projections + p-pass ----
    gemm64x2_tiled<<<(N0 + 63) / 64, blk, 0, stream>>>(x0, W0, m0, Wt, tm, N0);
    gemm64x2_tiled<<<(N1 + 63) / 64, blk, 0, stream>>>(x1, W1, m1, Ws, sm, N1);
    ppass_kernel<<<(2 * (N0 + N1) + 255) / 256, blk, 0, stream>>>(
        m0, m1, sm, tm, a0, a1, ans,
        pl0, pr0, pl1, pr1, pls, prs, plt, prt, N0, N1);

    // ---- fused pull gathers (scores on the fly) ----
    GDesc g0 = { cur0, m0, pl0, pr0, base0,
                 curT, sm, prt, pls, baseT,
                 out0, N0 };
    GDesc g1 = { cur1, m1, pl1, pr1, base1,
                 curS, tm, pls, prt, baseS,
                 out1, N1 };
    gather2_kernel<<<2048, blk, 0, stream>>>(g0, csrAll);
    gather2_kernel<<<2048, blk, 0, stream>>>(g1, csrAll);

    // ---- passthroughs x_2, x_3, x_4 ----
    hipMemcpyAsync(outp,          x2, (size_t)NP * sizeof(float), hipMemcpyDeviceToDevice, stream);
    hipMemcpyAsync(outp + NP,     x3, (size_t)NP * sizeof(float), hipMemcpyDeviceToDevice, stream);
    hipMemcpyAsync(outp + 2 * NP, x4, (size_t)NP * sizeof(float), hipMemcpyDeviceToDevice, stream);
}

// Round 8
// 513.012 us; speedup vs baseline: 1.2266x; 1.0384x over previous
//
#include <hip/hip_runtime.h>

#define CDIM 64
#define SLOPE 0.2f
#define NBANDS 8

__device__ __forceinline__ float lrelu(float v) { return v > 0.f ? v : SLOPE * v; }

// ---------------------------------------------------------------------------
// Tiled dual GEMM, shuffle-free: Ya = X@Wa, Yb = X@Wb.
// ---------------------------------------------------------------------------
__global__ void gemm64x2_tiled(const float* __restrict__ X,
                               const float* __restrict__ Wa, float* __restrict__ Ya,
                               const float* __restrict__ Wb, float* __restrict__ Yb,
                               int n)
{
    __shared__ float sX[64 * 68];
    __shared__ float sWaT[64 * 66];
    __shared__ float sWbT[64 * 66];
    const int tid = threadIdx.x;
    const int lane = tid & 63;
    const int q = tid >> 6;

    for (int idx = tid; idx < 4096; idx += 256) {
        int k = idx >> 6, c = idx & 63;
        sWaT[c * 66 + k] = Wa[idx];
        sWbT[c * 66 + k] = Wb[idx];
    }

    const int ntiles = (n + 63) >> 6;
    for (int tile = blockIdx.x; tile < ntiles; tile += gridDim.x) {
        const int rowbase = tile << 6;
        __syncthreads();
#pragma unroll
        for (int i = 0; i < 4; ++i) {
            int f = tid + i * 256;
            int r = f >> 4, k4 = f & 15;
            int row = rowbase + r;
            float4 v = make_float4(0.f, 0.f, 0.f, 0.f);
            if (row < n) v = *reinterpret_cast<const float4*>(X + (size_t)row * 64 + k4 * 4);
            *reinterpret_cast<float4*>(&sX[r * 68 + k4 * 4]) = v;
        }
        __syncthreads();

        const int r0 = q * 16;
        float accA[16], accB[16];
#pragma unroll
        for (int r = 0; r < 16; ++r) { accA[r] = 0.f; accB[r] = 0.f; }

        for (int k4 = 0; k4 < 16; ++k4) {
            const float2 wa0 = *reinterpret_cast<const float2*>(&sWaT[lane * 66 + k4 * 4]);
            const float2 wa1 = *reinterpret_cast<const float2*>(&sWaT[lane * 66 + k4 * 4 + 2]);
            const float2 wb0 = *reinterpret_cast<const float2*>(&sWbT[lane * 66 + k4 * 4]);
            const float2 wb1 = *reinterpret_cast<const float2*>(&sWbT[lane * 66 + k4 * 4 + 2]);
#pragma unroll
            for (int r = 0; r < 16; ++r) {
                const float4 xv = *reinterpret_cast<const float4*>(&sX[(r0 + r) * 68 + k4 * 4]);
                accA[r] = fmaf(xv.x, wa0.x, accA[r]);
                accA[r] = fmaf(xv.y, wa0.y, accA[r]);
                accA[r] = fmaf(xv.z, wa1.x, accA[r]);
                accA[r] = fmaf(xv.w, wa1.y, accA[r]);
                accB[r] = fmaf(xv.x, wb0.x, accB[r]);
                accB[r] = fmaf(xv.y, wb0.y, accB[r]);
                accB[r] = fmaf(xv.z, wb1.x, accB[r]);
                accB[r] = fmaf(xv.w, wb1.y, accB[r]);
            }
        }
#pragma unroll
        for (int r = 0; r < 16; ++r) {
            int row = rowbase + r0 + r;
            if (row < n) {
                Ya[(size_t)row * 64 + lane] = accA[r];
                Yb[(size_t)row * 64 + lane] = accB[r];
            }
        }
    }
}

// ---------------------------------------------------------------------------
// p-pass: one thread per row, dual dot product in-register.
// ---------------------------------------------------------------------------
__global__ void ppass_kernel(const float* __restrict__ m0, const float* __restrict__ m1,
                             const float* __restrict__ sm, const float* __restrict__ tm,
                             const float* __restrict__ a0, const float* __restrict__ a1,
                             const float* __restrict__ ans,
                             float* __restrict__ pl0, float* __restrict__ pr0,
                             float* __restrict__ pl1, float* __restrict__ pr1,
                             float* __restrict__ pls, float* __restrict__ prs,
                             float* __restrict__ plt, float* __restrict__ prt,
                             int N0, int N1)
{
    int g = blockIdx.x * blockDim.x + threadIdx.x;
    if (g >= 2 * (N0 + N1)) return;
    const float* M; const float* a; float* pL; float* pR; int r;
    if (g < N0)                { M = m0; a = a0;  pL = pl0; pR = pr0; r = g; }
    else if (g < N0 + N1)      { M = m1; a = a1;  pL = pl1; pR = pr1; r = g - N0; }
    else if (g < N0 + 2 * N1)  { M = sm; a = ans; pL = pls; pR = prs; r = g - N0 - N1; }
    else                       { M = tm; a = ans; pL = plt; pR = prt; r = g - N0 - 2 * N1; }

    const float4* row = reinterpret_cast<const float4*>(M + (size_t)r * 64);
    float sl = 0.f, sr = 0.f;
#pragma unroll
    for (int k4 = 0; k4 < 16; ++k4) {
        float4 xv = row[k4];
        float4 al = *reinterpret_cast<const float4*>(a + k4 * 4);
        float4 ar = *reinterpret_cast<const float4*>(a + 64 + k4 * 4);
        sl = fmaf(xv.x, al.x, sl); sl = fmaf(xv.y, al.y, sl);
        sl = fmaf(xv.z, al.z, sl); sl = fmaf(xv.w, al.w, sl);
        sr = fmaf(xv.x, ar.x, sr); sr = fmaf(xv.y, ar.y, sr);
        sr = fmaf(xv.z, ar.z, sr); sr = fmaf(xv.w, ar.w, sr);
    }
    pL[r] = sl;
    pR[r] = sr;
}

// ---------------------------------------------------------------------------
// Edge-list descriptor for fused count/fill over 4 lists.
// ---------------------------------------------------------------------------
struct EdgeLists {
    const int* keys[4];
    const int* vals[4];
    int* cur[4];
    int E[4];
    int N[4];     // row count per list (key domain size)
    int blk[5];   // cumulative block offsets per list (1024 edges/block)
};

__device__ __forceinline__ int list_of(const EdgeLists& d, int b)
{
    return (b >= d.blk[2]) ? ((b >= d.blk[3]) ? 3 : 2) : ((b >= d.blk[1]) ? 1 : 0);
}

// ---------------------------------------------------------------------------
// XCD-banded histogram. 1-D grid of nEdgeBlk*8 blocks:
//   band = blockIdx.x & 7  (round-robin dispatch -> all of band b's blocks
//   land on XCD b, so cur[] atomic window for band b stays in that XCD's L2)
//   chunk = blockIdx.x >> 3 picks the 1024-edge chunk.
// ---------------------------------------------------------------------------
__global__ void count_xcd(EdgeLists d)
{
    const int band = blockIdx.x & (NBANDS - 1);
    const int b = blockIdx.x >> 3;
    const int l = list_of(d, b);
    int base = (b - d.blk[l]) * 1024 + threadIdx.x * 4;
    const int E = d.E[l];
    if (base >= E) return;
    const int Nl = d.N[l];
    const int lo = (int)((size_t)band * Nl / NBANDS);
    const int hi = (int)((size_t)(band + 1) * Nl / NBANDS);
    int* cur = d.cur[l];

    if (base + 3 < E) {
        int4 k4 = *reinterpret_cast<const int4*>(d.keys[l] + base);
        if (k4.x >= lo && k4.x < hi) atomicAdd(&cur[k4.x], 1);
        if (k4.y >= lo && k4.y < hi) atomicAdd(&cur[k4.y], 1);
        if (k4.z >= lo && k4.z < hi) atomicAdd(&cur[k4.z], 1);
        if (k4.w >= lo && k4.w < hi) atomicAdd(&cur[k4.w], 1);
    } else {
        for (int u = base; u < E; ++u) {
            int k = d.keys[l][u];
            if (k >= lo && k < hi) atomicAdd(&cur[k], 1);
        }
    }
}

// ---------------------------------------------------------------------------
// XCD-banded CSR fill (same band<->XCD affinity as count_xcd). Band b's csr
// destination window (~E_tot/8 * 4B ~= 1.4 MB) + cursor window (~150 KB)
// stay in XCD b's L2, so each 64B csr line is write-combined in-cache and
// written back to HBM once instead of once per edge.
// ---------------------------------------------------------------------------
__global__ void fill_xcd(EdgeLists d, int* __restrict__ csr)
{
    const int band = blockIdx.x & (NBANDS - 1);
    const int b = blockIdx.x >> 3;
    const int l = list_of(d, b);
    int base = (b - d.blk[l]) * 1024 + threadIdx.x * 4;
    const int E = d.E[l];
    if (base >= E) return;
    const int Nl = d.N[l];
    const int lo = (int)((size_t)band * Nl / NBANDS);
    const int hi = (int)((size_t)(band + 1) * Nl / NBANDS);
    int* cur = d.cur[l];

    if (base + 3 < E) {
        int4 k4 = *reinterpret_cast<const int4*>(d.keys[l] + base);
        if (k4.x >= lo && k4.x < hi) {
            int pos = atomicAdd(&cur[k4.x], 1);
            csr[pos] = d.vals[l][base + 0];
        }
        if (k4.y >= lo && k4.y < hi) {
            int pos = atomicAdd(&cur[k4.y], 1);
            csr[pos] = d.vals[l][base + 1];
        }
        if (k4.z >= lo && k4.z < hi) {
            int pos = atomicAdd(&cur[k4.z], 1);
            csr[pos] = d.vals[l][base + 2];
        }
        if (k4.w >= lo && k4.w < hi) {
            int pos = atomicAdd(&cur[k4.w], 1);
            csr[pos] = d.vals[l][base + 3];
        }
    } else {
        for (int u = base; u < E; ++u) {
            int k = d.keys[l][u];
            if (k >= lo && k < hi) {
                int pos = atomicAdd(&cur[k], 1);
                csr[pos] = d.vals[l][u];
            }
        }
    }
}

// ---------------------------------------------------------------------------
// 3-kernel global exclusive scan over cnt[0..n), chunk = 2048/block.
// ---------------------------------------------------------------------------
#define SCAN_CHUNK 2048

__global__ void scan_partials(const int* __restrict__ cnt, int* __restrict__ part, int n)
{
    __shared__ int tsum[256];
    int b = blockIdx.x, t = threadIdx.x;
    int base = b * SCAN_CHUNK + t * 8;
    int s = 0;
#pragma unroll
    for (int u = 0; u < 8; ++u) { int idx = base + u; if (idx < n) s += cnt[idx]; }
    tsum[t] = s;
    __syncthreads();
    for (int off = 128; off; off >>= 1) {
        if (t < off) tsum[t] += tsum[t + off];
        __syncthreads();
    }
    if (t == 0) part[b] = tsum[0];
}

__global__ void scan_small(int* __restrict__ part, int n)
{
    __shared__ int sh[256];
    int t = threadIdx.x;
    sh[t] = (t < n) ? part[t] : 0;
    __syncthreads();
    for (int off = 1; off < 256; off <<= 1) {
        int x = (t >= off) ? sh[t - off] : 0;
        __syncthreads();
        sh[t] += x;
        __syncthreads();
    }
    if (t < n) part[t] = (t == 0) ? 0 : sh[t - 1];
}

__global__ void scan_apply(int* __restrict__ cnt, const int* __restrict__ part, int n)
{
    __shared__ int tsum[256];
    int b = blockIdx.x, t = threadIdx.x;
    int base = b * SCAN_CHUNK + t * 8;
    int v[8];
    int s = 0;
#pragma unroll
    for (int u = 0; u < 8; ++u) {
        int idx = base + u;
        v[u] = (idx < n) ? cnt[idx] : 0;
        s += v[u];
    }
    tsum[t] = s;
    __syncthreads();
    for (int off = 1; off < 256; off <<= 1) {
        int x = (t >= off) ? tsum[t - off] : 0;
        __syncthreads();
        tsum[t] += x;
        __syncthreads();
    }
    int pre = part[b] + ((t == 0) ? 0 : tsum[t - 1]);
#pragma unroll
    for (int u = 0; u < 8; ++u) {
        int idx = base + u;
        if (idx < n) cnt[idx] = pre;
        pre += v[u];
    }
}

// ---------------------------------------------------------------------------
// Fused dual pull-gather with on-the-fly scores:
//   out[r] = (1/denA) * sum e_A * MA[j]  +  (1/denB) * sum e_B * MB[j]
//   e = lrelu(pl[row] + pr[j]); den = sum e per row.
// ---------------------------------------------------------------------------
struct GDesc {
    const int* curA; const float* MA; const float* plA; const float* prA; int baseA;
    const int* curB; const float* MB; const float* plB; const float* prB; int baseB;
    float* out; int n;
};

__global__ void gather2_kernel(GDesc gd, const int* __restrict__ csr)
{
    const int lane = threadIdx.x & 63;
    const int g = lane >> 4;
    const int c4 = (lane & 15) << 2;
    int wave = (int)((blockIdx.x * blockDim.x + threadIdx.x) >> 6);
    int nw = (int)((gridDim.x * blockDim.x) >> 6);

    for (int r = wave; r < gd.n; r += nw) {
        float4 accA = make_float4(0.f, 0.f, 0.f, 0.f);
        float4 accB = make_float4(0.f, 0.f, 0.f, 0.f);
        float seA = 0.f, seB = 0.f;

        {
            const float pl = gd.plA[r];
            int p0 = (r == 0) ? gd.baseA : gd.curA[r - 1];
            int p1 = gd.curA[r];
#pragma unroll 4
            for (int p = p0; p < p1; p += 4) {
                int idx = p + g;
                bool ok = idx < p1;
                int j = ok ? __builtin_nontemporal_load(csr + idx) : 0;
                float e = ok ? lrelu(pl + gd.prA[j]) : 0.f;
                seA += e;
                const float4 row = *reinterpret_cast<const float4*>(gd.MA + (size_t)j * 64 + c4);
                accA.x = fmaf(e, row.x, accA.x);
                accA.y = fmaf(e, row.y, accA.y);
                accA.z = fmaf(e, row.z, accA.z);
                accA.w = fmaf(e, row.w, accA.w);
            }
        }
        {
            const float pl = gd.plB[r];
            int p0 = (r == 0) ? gd.baseB : gd.curB[r - 1];
            int p1 = gd.curB[r];
#pragma unroll 4
            for (int p = p0; p < p1; p += 4) {
                int idx = p + g;
                bool ok = idx < p1;
                int j = ok ? __builtin_nontemporal_load(csr + idx) : 0;
                float e = ok ? lrelu(pl + gd.prB[j]) : 0.f;
                seB += e;
                const float4 row = *reinterpret_cast<const float4*>(gd.MB + (size_t)j * 64 + c4);
                accB.x = fmaf(e, row.x, accB.x);
                accB.y = fmaf(e, row.y, accB.y);
                accB.z = fmaf(e, row.z, accB.z);
                accB.w = fmaf(e, row.w, accB.w);
            }
        }

        seA += __shfl_xor(seA, 16, 64); seA += __shfl_xor(seA, 32, 64);
        seB += __shfl_xor(seB, 16, 64); seB += __shfl_xor(seB, 32, 64);
        float rA = 1.f / ((seA == 0.f) ? 1.f : seA);
        float rB = 1.f / ((seB == 0.f) ? 1.f : seB);

        float4 part;
        part.x = accA.x * rA + accB.x * rB;
        part.y = accA.y * rA + accB.y * rB;
        part.z = accA.z * rA + accB.z * rB;
        part.w = accA.w * rA + accB.w * rB;
        part.x += __shfl_xor(part.x, 16, 64); part.x += __shfl_xor(part.x, 32, 64);
        part.y += __shfl_xor(part.y, 16, 64); part.y += __shfl_xor(part.y, 32, 64);
        part.z += __shfl_xor(part.z, 16, 64); part.z += __shfl_xor(part.z, 32, 64);
        part.w += __shfl_xor(part.w, 16, 64); part.w += __shfl_xor(part.w, 32, 64);

        if (g == 0) *reinterpret_cast<float4*>(gd.out + (size_t)r * 64 + c4) = part;
    }
}

extern "C" void kernel_launch(void* const* d_in, const int* in_sizes, int n_in,
                              void* d_out, int out_size, void* d_ws, size_t ws_size,
                              hipStream_t stream)
{
    const float* x0  = (const float*)d_in[0];
    const float* x1  = (const float*)d_in[1];
    const float* x2  = (const float*)d_in[2];
    const float* x3  = (const float*)d_in[3];
    const float* x4  = (const float*)d_in[4];
    const int*   adj0 = (const int*)d_in[5];
    const int*   adj1 = (const int*)d_in[6];
    const int*   inct = (const int*)d_in[7];
    const int*   incs = (const int*)d_in[8];
    const float* W0  = (const float*)d_in[9];
    const float* a0  = (const float*)d_in[10];
    const float* W1  = (const float*)d_in[11];
    const float* a1  = (const float*)d_in[12];
    const float* Ws  = (const float*)d_in[13];
    const float* Wt  = (const float*)d_in[14];
    const float* ans = (const float*)d_in[15];

    const int N0  = in_sizes[0] / CDIM;      // 50000
    const int N1  = in_sizes[1] / CDIM;      // 100000
    const int NP  = in_sizes[2];             // passthrough flat size
    const int E0  = in_sizes[5] / 2;         // 800000
    const int E1  = in_sizes[6] / 2;         // 1600000
    const int E01 = in_sizes[7];             // 200000

    float* out0 = (float*)d_out;
    float* out1 = out0 + (size_t)N0 * CDIM;
    float* outp = out1 + (size_t)N1 * CDIM;

    // ---- workspace layout ----
    char* w = (char*)d_ws;
    size_t off = 0;
    float* m0  = (float*)(w + off); off += (size_t)N0 * CDIM * 4;
    float* m1  = (float*)(w + off); off += (size_t)N1 * CDIM * 4;
    float* sm  = (float*)(w + off); off += (size_t)N1 * CDIM * 4;
    float* tm  = (float*)(w + off); off += (size_t)N0 * CDIM * 4;
    float* pl0 = (float*)(w + off); off += (size_t)N0 * 4;
    float* pr0 = (float*)(w + off); off += (size_t)N0 * 4;
    float* pl1 = (float*)(w + off); off += (size_t)N1 * 4;
    float* pr1 = (float*)(w + off); off += (size_t)N1 * 4;
    float* pls = (float*)(w + off); off += (size_t)N1 * 4;   // p_s = sm @ a_ns[:C]
    float* prs = (float*)(w + off); off += (size_t)N1 * 4;   // scratch
    float* plt = (float*)(w + off); off += (size_t)N0 * 4;   // scratch
    float* prt = (float*)(w + off); off += (size_t)N0 * 4;   // p_t = tm @ a_ns[C:]
    int* curAll = (int*)(w + off);
    int* cur0 = curAll;            // N0
    int* cur1 = cur0 + N0;         // N1
    int* curT = cur1 + N1;         // N0
    int* curS = curT + N0;         // N1
    const int Ntot = N0 + N1 + N0 + N1;
    off += (size_t)Ntot * 4;
    int* part = (int*)(w + off); off += 1024 * 4;
    int* csrAll = (int*)(w + off); off += ((size_t)E0 + E1 + 2 * (size_t)E01) * 4;
    (void)ws_size; (void)n_in; (void)out_size;

    const int base0 = 0;
    const int base1 = E0;
    const int baseT = E0 + E1;
    const int baseS = E0 + E1 + E01;

    dim3 blk(256);

    // ---- edge-list descriptors (1024 edges per block-chunk) ----
    EdgeLists d;
    d.keys[0] = adj0;      d.vals[0] = adj0 + E0; d.cur[0] = cur0; d.E[0] = E0;  d.N[0] = N0;
    d.keys[1] = adj1;      d.vals[1] = adj1 + E1; d.cur[1] = cur1; d.E[1] = E1;  d.N[1] = N1;
    d.keys[2] = inct;      d.vals[2] = incs;      d.cur[2] = curT; d.E[2] = E01; d.N[2] = N0;
    d.keys[3] = incs;      d.vals[3] = inct;      d.cur[3] = curS; d.E[3] = E01; d.N[3] = N1;
    d.blk[0] = 0;
    for (int l = 0; l < 4; ++l) d.blk[l + 1] = d.blk[l] + (d.E[l] + 1023) / 1024;
    const int nEdgeBlk = d.blk[4];

    // ---- CSR build: count -> global scan -> fill, all XCD-banded ----
    hipMemsetAsync(curAll, 0, (size_t)Ntot * 4, stream);
    count_xcd<<<nEdgeBlk * NBANDS, blk, 0, stream>>>(d);

    int nCh = (Ntot + SCAN_CHUNK - 1) / SCAN_CHUNK;
    scan_partials<<<nCh, blk, 0, stream>>>(curAll, part, Ntot);
    scan_small<<<1, blk, 0, stream>>>(part, nCh);
    scan_apply<<<nCh, blk, 0, stream>>>(curAll, part, Ntot);

    fill_xcd<<<nEdgeBlk * NBANDS, blk, 0, stream>>>(d, csrAll);

    // ---- dense projections + p-pass ----
    gemm64x2_tiled<<<(N0 + 63) / 64, blk, 0, stream>>>(x0, W0, m0, Wt, tm, N0);
    gemm64x2_tiled<<<(N1 + 63) / 64, blk, 0, stream>>>(x1, W1, m1, Ws, sm, N1);
    ppass_kernel<<<(2 * (N0 + N1) + 255) / 256, blk, 0, stream>>>(
        m0, m1, sm, tm, a0, a1, ans,
        pl0, pr0, pl1, pr1, pls, prs, plt, prt, N0, N1);

    // ---- fused pull gathers (scores on the fly) ----
    GDesc g0 = { cur0, m0, pl0, pr0, base0,
                 curT, sm, prt, pls, baseT,
                 out0, N0 };
    GDesc g1 = { cur1, m1, pl1, pr1, base1,
                 curS, tm, pls, prt, baseS,
                 out1, N1 };
    gather2_kernel<<<2048, blk, 0, stream>>>(g0, csrAll);
    gather2_kernel<<<2048, blk, 0, stream>>>(g1, csrAll);

    // ---- passthroughs x_2, x_3, x_4 ----
    hipMemcpyAsync(outp,          x2, (size_t)NP * sizeof(float), hipMemcpyDeviceToDevice, stream);
    hipMemcpyAsync(outp + NP,     x3, (size_t)NP * sizeof(float), hipMemcpyDeviceToDevice, stream);
    hipMemcpyAsync(outp + 2 * NP, x4, (size_t)NP * sizeof(float), hipMemcpyDeviceToDevice, stream);
}